// Round 6
// baseline (4761.015 us; speedup 1.0000x reference)
//
#include <hip/hip_runtime.h>
#include <hip/hip_bf16.h>
#include <math.h>

#define BB 8
#define NN 1024
#define KK 40
#define EMBD 1024
#define EPSF 1e-5f

// ---------------- knn: one BLOCK per query row; LDS tree top-40 by -||x_n - x_m||^2 ----------------
__global__ __launch_bounds__(256) void knn_block_kernel(const float* __restrict__ x, int C, int bstride,
                                                        int* __restrict__ gidx) {
    __shared__ float srow[NN];
    __shared__ float sv[256];
    __shared__ int   si[256];
    int tid = threadIdx.x;
    int b = blockIdx.x >> 10, n = blockIdx.x & 1023;
    const float* xb = x + (size_t)b * bstride;

    float acc[4];
#pragma unroll
    for (int j = 0; j < 4; ++j) acc[j] = 0.f;
    for (int c = 0; c < C; ++c) {
        float xn = xb[c * NN + n];
#pragma unroll
        for (int j = 0; j < 4; ++j) {
            float d = xb[c * NN + tid + 256 * j] - xn;
            acc[j] = fmaf(-d, d, acc[j]);
        }
    }
#pragma unroll
    for (int j = 0; j < 4; ++j) srow[tid + 256 * j] = acc[j];
    __syncthreads();

    int* gi = gidx + (size_t)(b * NN + n) * KK;
    for (int it = 0; it < KK; ++it) {
        float bv = srow[tid]; int bi = tid;
#pragma unroll
        for (int j = 1; j < 4; ++j) {
            int m = tid + 256 * j;
            float t = srow[m];
            if (t > bv) { bv = t; bi = m; }      // ascending m: keeps lowest index on ties
        }
        sv[tid] = bv; si[tid] = bi;
        __syncthreads();
        for (int s = 128; s >= 1; s >>= 1) {
            if (tid < s) {
                float ov = sv[tid + s]; int oi = si[tid + s];
                if (ov > sv[tid] || (ov == sv[tid] && oi < si[tid])) { sv[tid] = ov; si[tid] = oi; }
            }
            __syncthreads();
        }
        if (tid == 0) { gi[it] = si[0]; srow[si[0]] = -INFINITY; }
        __syncthreads();
    }
}

// ---------------- fully naive edge conv: out = max_k lrelu(bn(w·[x_m-x_n ; x_n])) ----------------
__global__ __launch_bounds__(256) void conv_naive_kernel(const float* __restrict__ x, int C, int bstride,
                                                         const float* __restrict__ w, const float* __restrict__ bnp,
                                                         int O, const int* __restrict__ gidx,
                                                         float* __restrict__ outp) {
    extern __shared__ float ws[];                // 8 * 2C floats
    int tid = threadIdx.x;
    int opb = O >> 3;
    int nt   = blockIdx.x & 3;
    int rest = blockIdx.x >> 2;
    int oc = rest % opb;
    int b  = rest / opb;
    int o0 = oc << 3;
    int n  = (nt << 8) + tid;
    const float* xb = x + (size_t)b * bstride;
    int C2 = 2 * C;

    for (int t = tid; t < 8 * C2; t += 256)
        ws[t] = w[(size_t)(o0 + t / C2) * C2 + (t % C2)];
    __syncthreads();

    float sc[8], mu[8], be[8];
#pragma unroll
    for (int r = 0; r < 8; ++r) {
        int o = o0 + r;
        sc[r] = bnp[o] * rsqrtf(bnp[3 * O + o] + EPSF);
        mu[r] = bnp[2 * O + o];
        be[r] = bnp[O + o];
    }

    const int* gi = gidx + (size_t)(b * NN + n) * KK;
    float hmax[8];
#pragma unroll
    for (int r = 0; r < 8; ++r) hmax[r] = -INFINITY;

    for (int k = 0; k < KK; ++k) {
        int m = gi[k];
        float acc[8];
#pragma unroll
        for (int r = 0; r < 8; ++r) acc[r] = 0.f;
        for (int c = 0; c < C; ++c) {
            float xm = xb[c * NN + m];
            float xn = xb[c * NN + n];
            float d = xm - xn;
#pragma unroll
            for (int r = 0; r < 8; ++r) {
                acc[r] = fmaf(ws[r * C2 + c], d, acc[r]);        // w_a · (x_m - x_n)
                acc[r] = fmaf(ws[r * C2 + C + c], xn, acc[r]);   // w_b · x_n
            }
        }
#pragma unroll
        for (int r = 0; r < 8; ++r) {
            float t0 = (acc[r] - mu[r]) * sc[r] + be[r];
            t0 = t0 >= 0.f ? t0 : 0.2f * t0;                     // lrelu BEFORE max (ref order)
            hmax[r] = fmaxf(hmax[r], t0);
        }
    }
#pragma unroll
    for (int r = 0; r < 8; ++r)
        outp[(size_t)b * 512 * NN + (size_t)(o0 + r) * NN + n] = hmax[r];
}

// ---------------- naive emb: one block per (b,o); e=lrelu(bn5(w5·xc)); max+mean over N ----------------
__global__ __launch_bounds__(256) void emb_naive_kernel(const float* __restrict__ xc, const float* __restrict__ w5,
                                                        const float* __restrict__ bnp, float* __restrict__ g) {
    __shared__ float smax[256], ssum[256];
    int tid = threadIdx.x;
    int b = blockIdx.x >> 10, o = blockIdx.x & 1023;
    const float* xcb = xc + (size_t)b * 512 * NN;
    const float* wr  = w5 + (size_t)o * 512;
    float sc = bnp[o] * rsqrtf(bnp[3 * EMBD + o] + EPSF);
    float mu = bnp[2 * EMBD + o], be = bnp[EMBD + o];
    float vmax = -INFINITY, vsum = 0.f;
#pragma unroll
    for (int jj = 0; jj < 4; ++jj) {
        int n = tid + (jj << 8);
        float s = 0.f;
        for (int c = 0; c < 512; ++c) s = fmaf(wr[c], xcb[c * NN + n], s);
        float t0 = (s - mu) * sc + be;
        t0 = t0 >= 0.f ? t0 : 0.2f * t0;
        vmax = fmaxf(vmax, t0);
        vsum += t0;
    }
    smax[tid] = vmax; ssum[tid] = vsum;
    __syncthreads();
    for (int s = 128; s >= 1; s >>= 1) {
        if (tid < s) {
            smax[tid] = fmaxf(smax[tid], smax[tid + s]);
            ssum[tid] += ssum[tid + s];
        }
        __syncthreads();
    }
    if (tid == 0) {
        g[(size_t)b * 2 * EMBD + o]        = smax[0];
        g[(size_t)b * 2 * EMBD + EMBD + o] = ssum[0] * (1.0f / 1024.0f);
    }
}

// ---------------- naive head1: one block per (b,o) ----------------
__global__ __launch_bounds__(256) void head1_naive_kernel(const float* __restrict__ g, const float* __restrict__ l1,
                                                          const float* __restrict__ bnp, float* __restrict__ h1) {
    __shared__ float red[256];
    int tid = threadIdx.x;
    int b = blockIdx.x >> 9, o = blockIdx.x & 511;
    const float* gr = g + (size_t)b * 2 * EMBD;
    const float* lr = l1 + (size_t)o * 2 * EMBD;
    float s = 0.f;
    for (int c = tid; c < 2048; c += 256) s = fmaf(gr[c], lr[c], s);
    red[tid] = s;
    __syncthreads();
    for (int st = 128; st >= 1; st >>= 1) {
        if (tid < st) red[tid] += red[tid + st];
        __syncthreads();
    }
    if (tid == 0) {
        float sc = bnp[o] * rsqrtf(bnp[3 * 512 + o] + EPSF);
        float t0 = (red[0] - bnp[2 * 512 + o]) * sc + bnp[512 + o];
        h1[b * 512 + o] = t0 >= 0.f ? t0 : 0.2f * t0;
    }
}

// ---------------- naive head2: one block per (b,o) ----------------
__global__ __launch_bounds__(256) void head2_naive_kernel(const float* __restrict__ h1, const float* __restrict__ l2w,
                                                          const float* __restrict__ l2b, const float* __restrict__ bnp,
                                                          float* __restrict__ h2) {
    __shared__ float red[256];
    int tid = threadIdx.x;
    int b = blockIdx.x >> 8, o = blockIdx.x & 255;
    const float* hr = h1 + (size_t)b * 512;
    const float* lr = l2w + (size_t)o * 512;
    float s = fmaf(hr[tid], lr[tid], hr[tid + 256] * lr[tid + 256]);
    red[tid] = s;
    __syncthreads();
    for (int st = 128; st >= 1; st >>= 1) {
        if (tid < st) red[tid] += red[tid + st];
        __syncthreads();
    }
    if (tid == 0) {
        float v = red[0] + l2b[o];
        float sc = bnp[o] * rsqrtf(bnp[3 * 256 + o] + EPSF);
        float t0 = (v - bnp[2 * 256 + o]) * sc + bnp[256 + o];
        h2[b * 256 + o] = t0 >= 0.f ? t0 : 0.2f * t0;
    }
}

// ---------------- naive head3: one block per (b,i) -> logits scratch ----------------
__global__ __launch_bounds__(256) void head3_naive_kernel(const float* __restrict__ h2, const float* __restrict__ l3w,
                                                          const float* __restrict__ l3b, float* __restrict__ logits) {
    __shared__ float red[256];
    int tid = threadIdx.x;
    int b = blockIdx.x / 40, i = blockIdx.x % 40;
    red[tid] = h2[(size_t)b * 256 + tid] * l3w[(size_t)i * 256 + tid];
    __syncthreads();
    for (int st = 128; st >= 1; st >>= 1) {
        if (tid < st) red[tid] += red[tid + st];
        __syncthreads();
    }
    if (tid == 0) logits[b * 40 + i] = red[0] + l3b[i];
}

// ---------------- final: out[0..319]=logits (f32), out[320..639]=log_softmax (f32) ----------------
__global__ void final_kernel(const float* __restrict__ logits, float* __restrict__ outp) {
    int b = blockIdx.x;
    if (threadIdx.x != 0) return;
    const float* lr = logits + b * 40;
    float mx = lr[0];
    for (int i = 1; i < 40; ++i) mx = fmaxf(mx, lr[i]);
    float se = 0.f;
    for (int i = 0; i < 40; ++i) se += expf(lr[i] - mx);
    float lse = logf(se);
    for (int i = 0; i < 40; ++i) {
        outp[b * 40 + i]            = lr[i];
        outp[BB * 40 + b * 40 + i]  = lr[i] - mx - lse;
    }
}

extern "C" void kernel_launch(void* const* d_in, const int* in_sizes, int n_in,
                              void* d_out, int out_size, void* d_ws, size_t ws_size,
                              hipStream_t stream) {
    const float* x   = (const float*)d_in[0];
    const float* w1  = (const float*)d_in[1];
    const float* w2  = (const float*)d_in[2];
    const float* w3  = (const float*)d_in[3];
    const float* w4  = (const float*)d_in[4];
    const float* w5  = (const float*)d_in[5];
    const float* l1  = (const float*)d_in[6];
    const float* l2w = (const float*)d_in[7];
    const float* l2b = (const float*)d_in[8];
    const float* l3w = (const float*)d_in[9];
    const float* l3b = (const float*)d_in[10];
    const float* bn1 = (const float*)d_in[11];
    const float* bn2 = (const float*)d_in[12];
    const float* bn3 = (const float*)d_in[13];
    const float* bn4 = (const float*)d_in[14];
    const float* bn5 = (const float*)d_in[15];
    const float* bn6 = (const float*)d_in[16];
    const float* bn7 = (const float*)d_in[17];
    float* outp = (float*)d_out;   // reference outputs are float32

    // workspace carve (floats): xc[8*512*1024] | gidx | g | h1 | h2 | logits
    float* xc     = (float*)d_ws;
    int*  gidx    = (int*)(xc + (size_t)BB * 512 * NN);
    float* g      = (float*)(gidx + (size_t)BB * NN * KK);
    float* h1     = g  + BB * 2 * EMBD;
    float* h2     = h1 + BB * 512;
    float* logits = h2 + BB * 256;

    struct Layer { const float* xin; int C; int bstride; const float* w; const float* bn; int O; float* out; };
    Layer L[4] = {
        { x,            3,   3 * NN,   w1, bn1, 64,  xc            },
        { xc,           64,  512 * NN, w2, bn2, 64,  xc + 64 * NN  },
        { xc + 64 * NN, 64,  512 * NN, w3, bn3, 128, xc + 128 * NN },
        { xc + 128 * NN,128, 512 * NN, w4, bn4, 256, xc + 256 * NN },
    };

    for (int i = 0; i < 4; ++i) {
        knn_block_kernel<<<dim3(BB * NN), dim3(256), 0, stream>>>(L[i].xin, L[i].C, L[i].bstride, gidx);
        size_t wlds = (size_t)8 * 2 * L[i].C * sizeof(float);
        conv_naive_kernel<<<dim3(BB * (L[i].O >> 3) * 4), dim3(256), wlds, stream>>>(
            L[i].xin, L[i].C, L[i].bstride, L[i].w, L[i].bn, L[i].O, gidx, L[i].out);
    }
    emb_naive_kernel<<<dim3(BB * NN), dim3(256), 0, stream>>>(xc, w5, bn5, g);
    head1_naive_kernel<<<dim3(BB * 512), dim3(256), 0, stream>>>(g, l1, bn6, h1);
    head2_naive_kernel<<<dim3(BB * 256), dim3(256), 0, stream>>>(h1, l2w, l2b, bn7, h2);
    head3_naive_kernel<<<dim3(BB * 40), dim3(256), 0, stream>>>(h2, l3w, l3b, logits);
    final_kernel<<<dim3(BB), dim3(64), 0, stream>>>(logits, outp);
}

// Round 7
// 990.544 us; speedup vs baseline: 4.8065x; 4.8065x over previous
//
#include <hip/hip_runtime.h>
#include <hip/hip_bf16.h>
#include <math.h>

#define BB 8
#define NN 1024
#define KK 40
#define EMBD 1024
#define EPSF 1e-5f
#define ROWS 8

// ---------------- xx[b,m] = sum_c x[b,c,m]^2 ----------------
__global__ __launch_bounds__(256) void xx_kernel(const float* __restrict__ x, int C, int bstride,
                                                 float* __restrict__ xx) {
    int idx = blockIdx.x * 256 + threadIdx.x;
    int b = idx >> 10, m = idx & 1023;
    const float* xb = x + (size_t)b * bstride;
    float s = 0.f;
    for (int c = 0; c < C; ++c) { float v = xb[c * NN + m]; s += v * v; }
    xx[idx] = s;
}

// ---------------- knn: 8 query rows per block, tiled panel, register selection ----------------
__global__ __launch_bounds__(256) void knn_kernel(const float* __restrict__ x, int C, int bstride,
                                                  const float* __restrict__ xx, int* __restrict__ gidx) {
    __shared__ float S[ROWS * NN];       // 32 KB
    __shared__ float CENT[64 * ROWS];    // 2 KB
    int tid = threadIdx.x;
    int b = blockIdx.x >> 7;             // NN/ROWS = 128 blocks per batch
    int n0 = (blockIdx.x & 127) * ROWS;
    const float* xb = x + (size_t)b * bstride;

    float acc[ROWS][4];
#pragma unroll
    for (int r = 0; r < ROWS; ++r)
#pragma unroll
        for (int j = 0; j < 4; ++j) acc[r][j] = 0.f;

    for (int c0 = 0; c0 < C; c0 += 64) {
        int cc = C - c0; if (cc > 64) cc = 64;
        for (int t = tid; t < cc * ROWS; t += 256)
            CENT[t] = xb[(c0 + t / ROWS) * NN + n0 + (t & (ROWS - 1))];
        __syncthreads();
        for (int ci = 0; ci < cc; ++ci) {
            float xm[4];
#pragma unroll
            for (int j = 0; j < 4; ++j) xm[j] = xb[(c0 + ci) * NN + tid + 256 * j];
#pragma unroll
            for (int r = 0; r < ROWS; ++r) {
                float ce = CENT[ci * ROWS + r];
#pragma unroll
                for (int j = 0; j < 4; ++j) acc[r][j] = fmaf(ce, xm[j], acc[r][j]);
            }
        }
        __syncthreads();
    }
    {
        float xv[4];
#pragma unroll
        for (int j = 0; j < 4; ++j) xv[j] = xx[b * NN + tid + 256 * j];
#pragma unroll
        for (int r = 0; r < ROWS; ++r)
#pragma unroll
            for (int j = 0; j < 4; ++j)
                S[r * NN + tid + 256 * j] = 2.f * acc[r][j] - xv[j];
    }
    __syncthreads();

    // selection: each wave owns 2 rows; 64 lanes x 16 values in registers
    int wave = tid >> 6, lane = tid & 63;
    for (int rr = 0; rr < ROWS / 4; ++rr) {
        int r = wave * (ROWS / 4) + rr;
        float xxn = xx[b * NN + n0 + r];
        float v[16];
#pragma unroll
        for (int j = 0; j < 16; ++j) v[j] = S[r * NN + lane + 64 * j] - xxn;
        int* gi = gidx + ((size_t)b * NN + n0 + r) * KK;
        for (int it = 0; it < KK; ++it) {
            float bv = v[0]; int bj = 0;
#pragma unroll
            for (int j = 1; j < 16; ++j) if (v[j] > bv) { bv = v[j]; bj = j; }
            int bm = lane + 64 * bj;
#pragma unroll
            for (int off = 32; off >= 1; off >>= 1) {
                float ov = __shfl_xor(bv, off);
                int   om = __shfl_xor(bm, off);
                if (ov > bv || (ov == bv && om < bm)) { bv = ov; bm = om; }
            }
            if (lane == 0) gi[it] = bm;
#pragma unroll
            for (int j = 0; j < 16; ++j) if (lane + 64 * j == bm) v[j] = -INFINITY;
        }
    }
}

// ---------------- ya = w_a @ x ; yc = (w_b - w_a) @ x ----------------
__global__ __launch_bounds__(256) void yab_kernel(const float* __restrict__ x, int C, int bstride,
                                                  const float* __restrict__ w, int O,
                                                  float* __restrict__ ya, float* __restrict__ yc) {
    int tid = threadIdx.x;
    int opb = O >> 3;
    int b  = blockIdx.x / opb;
    int o0 = (blockIdx.x % opb) << 3;
    const float* xb = x + (size_t)b * bstride;
    float a[8][4], cv[8][4];
#pragma unroll
    for (int r = 0; r < 8; ++r)
#pragma unroll
        for (int j = 0; j < 4; ++j) { a[r][j] = 0.f; cv[r][j] = 0.f; }
    for (int c = 0; c < C; ++c) {
        float xm[4];
#pragma unroll
        for (int j = 0; j < 4; ++j) xm[j] = xb[c * NN + tid + 256 * j];
#pragma unroll
        for (int r = 0; r < 8; ++r) {
            const float* wr = w + (size_t)(o0 + r) * 2 * C;
            float wa = wr[c];
            float wc = wr[C + c] - wa;
#pragma unroll
            for (int j = 0; j < 4; ++j) {
                a[r][j]  = fmaf(wa, xm[j], a[r][j]);
                cv[r][j] = fmaf(wc, xm[j], cv[r][j]);
            }
        }
    }
#pragma unroll
    for (int r = 0; r < 8; ++r)
#pragma unroll
        for (int j = 0; j < 4; ++j) {
            size_t off = ((size_t)b * O + o0 + r) * NN + tid + 256 * j;
            ya[off] = a[r][j];
            yc[off] = cv[r][j];
        }
}

// ---------------- gmax: out = lrelu(bn(max_k ya[o][idx]+yc[o][n])), 8 o-rows LDS-staged ----------------
__global__ __launch_bounds__(256) void gmax8_kernel(const float* __restrict__ ya, const float* __restrict__ yc,
                                                    const int* __restrict__ gidx, const float* __restrict__ bnp,
                                                    int O, float* __restrict__ outp, int out_bstride) {
    __shared__ float yrow[8 * NN];       // 32 KB
    int tid = threadIdx.x;
    int nt   = blockIdx.x & 3;
    int rest = blockIdx.x >> 2;
    int opb = O >> 3;
    int oc = rest % opb;
    int b  = rest / opb;
    int o0 = oc << 3;
    int n  = (nt << 8) + tid;

    for (int t = tid; t < 8 * NN; t += 256)
        yrow[t] = ya[((size_t)b * O + o0 + (t >> 10)) * NN + (t & 1023)];
    __syncthreads();

    int idx[KK];
    const int* gi = gidx + ((size_t)b * NN + n) * KK;
#pragma unroll
    for (int k = 0; k < KK; ++k) idx[k] = gi[k];

#pragma unroll
    for (int r = 0; r < 8; ++r) {
        float m = -INFINITY;
#pragma unroll 8
        for (int k = 0; k < KK; ++k) m = fmaxf(m, yrow[r * NN + idx[k]]);
        m += yc[((size_t)b * O + o0 + r) * NN + n];
        int o = o0 + r;
        float sc = bnp[o] * rsqrtf(bnp[3 * O + o] + EPSF);
        float t0 = (m - bnp[2 * O + o]) * sc + bnp[O + o];
        outp[(size_t)b * out_bstride + (size_t)o * NN + n] = t0 >= 0.f ? t0 : 0.2f * t0;
    }
}

// ---------------- e = lrelu(bn5(w5 @ xc)) fused with max+mean pooling over N ----------------
__global__ __launch_bounds__(256) void emb_kernel(const float* __restrict__ xc, const float* __restrict__ w5,
                                                  const float* __restrict__ bnp, float* __restrict__ g) {
    int tid = threadIdx.x;
    int b  = blockIdx.x >> 6;
    int o0 = (blockIdx.x & 63) << 4;
    const float* xcb = xc + (size_t)b * 512 * NN;
    float acc[16][4];
#pragma unroll
    for (int r = 0; r < 16; ++r)
#pragma unroll
        for (int j = 0; j < 4; ++j) acc[r][j] = 0.f;
    for (int c = 0; c < 512; ++c) {
        float xv[4];
#pragma unroll
        for (int j = 0; j < 4; ++j) xv[j] = xcb[c * NN + tid + 256 * j];
#pragma unroll
        for (int r = 0; r < 16; ++r) {
            float wv = w5[(size_t)(o0 + r) * 512 + c];
#pragma unroll
            for (int j = 0; j < 4; ++j) acc[r][j] = fmaf(wv, xv[j], acc[r][j]);
        }
    }
    int lane = tid & 63, wave = tid >> 6;
    __shared__ float rmax[16][4], rsum[16][4];
#pragma unroll
    for (int r = 0; r < 16; ++r) {
        int o = o0 + r;
        float sc = bnp[o] * rsqrtf(bnp[3 * EMBD + o] + EPSF);
        float mu = bnp[2 * EMBD + o], be = bnp[EMBD + o];
        float vmax = -INFINITY, vsum = 0.f;
#pragma unroll
        for (int j = 0; j < 4; ++j) {
            float t0 = (acc[r][j] - mu) * sc + be;
            t0 = t0 >= 0.f ? t0 : 0.2f * t0;
            vmax = fmaxf(vmax, t0);
            vsum += t0;
        }
#pragma unroll
        for (int off = 32; off >= 1; off >>= 1) {
            vmax = fmaxf(vmax, __shfl_xor(vmax, off));
            vsum += __shfl_xor(vsum, off);
        }
        if (lane == 0) { rmax[r][wave] = vmax; rsum[r][wave] = vsum; }
    }
    __syncthreads();
    if (tid < 16) {
        float vm = fmaxf(fmaxf(rmax[tid][0], rmax[tid][1]), fmaxf(rmax[tid][2], rmax[tid][3]));
        float vs = rsum[tid][0] + rsum[tid][1] + rsum[tid][2] + rsum[tid][3];
        g[(size_t)b * 2 * EMBD + o0 + tid] = vm;
        g[(size_t)b * 2 * EMBD + EMBD + o0 + tid] = vs * (1.0f / 1024.0f);
    }
}

// ---------------- naive head1: one block per (b,o) ----------------
__global__ __launch_bounds__(256) void head1_naive_kernel(const float* __restrict__ g, const float* __restrict__ l1,
                                                          const float* __restrict__ bnp, float* __restrict__ h1) {
    __shared__ float red[256];
    int tid = threadIdx.x;
    int b = blockIdx.x >> 9, o = blockIdx.x & 511;
    const float* gr = g + (size_t)b * 2 * EMBD;
    const float* lr = l1 + (size_t)o * 2 * EMBD;
    float s = 0.f;
    for (int c = tid; c < 2048; c += 256) s = fmaf(gr[c], lr[c], s);
    red[tid] = s;
    __syncthreads();
    for (int st = 128; st >= 1; st >>= 1) {
        if (tid < st) red[tid] += red[tid + st];
        __syncthreads();
    }
    if (tid == 0) {
        float sc = bnp[o] * rsqrtf(bnp[3 * 512 + o] + EPSF);
        float t0 = (red[0] - bnp[2 * 512 + o]) * sc + bnp[512 + o];
        h1[b * 512 + o] = t0 >= 0.f ? t0 : 0.2f * t0;
    }
}

// ---------------- naive head2: one block per (b,o) ----------------
__global__ __launch_bounds__(256) void head2_naive_kernel(const float* __restrict__ h1, const float* __restrict__ l2w,
                                                          const float* __restrict__ l2b, const float* __restrict__ bnp,
                                                          float* __restrict__ h2) {
    __shared__ float red[256];
    int tid = threadIdx.x;
    int b = blockIdx.x >> 8, o = blockIdx.x & 255;
    const float* hr = h1 + (size_t)b * 512;
    const float* lr = l2w + (size_t)o * 512;
    float s = fmaf(hr[tid], lr[tid], hr[tid + 256] * lr[tid + 256]);
    red[tid] = s;
    __syncthreads();
    for (int st = 128; st >= 1; st >>= 1) {
        if (tid < st) red[tid] += red[tid + st];
        __syncthreads();
    }
    if (tid == 0) {
        float v = red[0] + l2b[o];
        float sc = bnp[o] * rsqrtf(bnp[3 * 256 + o] + EPSF);
        float t0 = (v - bnp[2 * 256 + o]) * sc + bnp[256 + o];
        h2[b * 256 + o] = t0 >= 0.f ? t0 : 0.2f * t0;
    }
}

// ---------------- naive head3: one block per (b,i) -> logits scratch ----------------
__global__ __launch_bounds__(256) void head3_naive_kernel(const float* __restrict__ h2, const float* __restrict__ l3w,
                                                          const float* __restrict__ l3b, float* __restrict__ logits) {
    __shared__ float red[256];
    int tid = threadIdx.x;
    int b = blockIdx.x / 40, i = blockIdx.x % 40;
    red[tid] = h2[(size_t)b * 256 + tid] * l3w[(size_t)i * 256 + tid];
    __syncthreads();
    for (int st = 128; st >= 1; st >>= 1) {
        if (tid < st) red[tid] += red[tid + st];
        __syncthreads();
    }
    if (tid == 0) logits[b * 40 + i] = red[0] + l3b[i];
}

// ---------------- final: out[0..319]=logits (f32), out[320..639]=log_softmax (f32) ----------------
__global__ void final_kernel(const float* __restrict__ logits, float* __restrict__ outp) {
    int b = blockIdx.x;
    if (threadIdx.x != 0) return;
    const float* lr = logits + b * 40;
    float mx = lr[0];
    for (int i = 1; i < 40; ++i) mx = fmaxf(mx, lr[i]);
    float se = 0.f;
    for (int i = 0; i < 40; ++i) se += expf(lr[i] - mx);
    float lse = logf(se);
    for (int i = 0; i < 40; ++i) {
        outp[b * 40 + i]            = lr[i];
        outp[BB * 40 + b * 40 + i]  = lr[i] - mx - lse;
    }
}

extern "C" void kernel_launch(void* const* d_in, const int* in_sizes, int n_in,
                              void* d_out, int out_size, void* d_ws, size_t ws_size,
                              hipStream_t stream) {
    const float* x   = (const float*)d_in[0];
    const float* w1  = (const float*)d_in[1];
    const float* w2  = (const float*)d_in[2];
    const float* w3  = (const float*)d_in[3];
    const float* w4  = (const float*)d_in[4];
    const float* w5  = (const float*)d_in[5];
    const float* l1  = (const float*)d_in[6];
    const float* l2w = (const float*)d_in[7];
    const float* l2b = (const float*)d_in[8];
    const float* l3w = (const float*)d_in[9];
    const float* l3b = (const float*)d_in[10];
    const float* bn1 = (const float*)d_in[11];
    const float* bn2 = (const float*)d_in[12];
    const float* bn3 = (const float*)d_in[13];
    const float* bn4 = (const float*)d_in[14];
    const float* bn5 = (const float*)d_in[15];
    const float* bn6 = (const float*)d_in[16];
    const float* bn7 = (const float*)d_in[17];
    float* outp = (float*)d_out;   // reference outputs are float32

    // workspace carve (floats): xc[8*512*1024] | ya[8*256*1024] | yc[...] | xx | gidx | g | h1 | h2 | logits
    float* xc     = (float*)d_ws;
    float* ya     = xc  + (size_t)BB * 512 * NN;
    float* ycb    = ya  + (size_t)BB * 256 * NN;
    float* xxb    = ycb + (size_t)BB * 256 * NN;
    int*  gidx    = (int*)(xxb + BB * NN);
    float* g      = (float*)(gidx + (size_t)BB * NN * KK);
    float* h1     = g  + BB * 2 * EMBD;
    float* h2     = h1 + BB * 512;
    float* logits = h2 + BB * 256;

    struct Layer { const float* xin; int C; int bstride; const float* w; const float* bn; int O; float* out; };
    Layer L[4] = {
        { x,            3,   3 * NN,   w1, bn1, 64,  xc            },
        { xc,           64,  512 * NN, w2, bn2, 64,  xc + 64 * NN  },
        { xc + 64 * NN, 64,  512 * NN, w3, bn3, 128, xc + 128 * NN },
        { xc + 128 * NN,128, 512 * NN, w4, bn4, 256, xc + 256 * NN },
    };

    for (int i = 0; i < 4; ++i) {
        xx_kernel<<<dim3(BB * NN / 256), dim3(256), 0, stream>>>(L[i].xin, L[i].C, L[i].bstride, xxb);
        knn_kernel<<<dim3(BB * (NN / ROWS)), dim3(256), 0, stream>>>(L[i].xin, L[i].C, L[i].bstride, xxb, gidx);
        yab_kernel<<<dim3(BB * L[i].O / 8), dim3(256), 0, stream>>>(L[i].xin, L[i].C, L[i].bstride, L[i].w, L[i].O, ya, ycb);
        gmax8_kernel<<<dim3(BB * (L[i].O / 8) * 4), dim3(256), 0, stream>>>(ya, ycb, gidx, L[i].bn, L[i].O, L[i].out, 512 * NN);
    }
    emb_kernel<<<dim3(BB * 64), dim3(256), 0, stream>>>(xc, w5, bn5, g);
    head1_naive_kernel<<<dim3(BB * 512), dim3(256), 0, stream>>>(g, l1, bn6, h1);
    head2_naive_kernel<<<dim3(BB * 256), dim3(256), 0, stream>>>(h1, l2w, l2b, bn7, h2);
    head3_naive_kernel<<<dim3(BB * 40), dim3(256), 0, stream>>>(h2, l3w, l3b, logits);
    final_kernel<<<dim3(BB), dim3(64), 0, stream>>>(logits, outp);
}